// Round 1
// baseline (326.923 us; speedup 1.0000x reference)
//
#include <hip/hip_runtime.h>
#include <cstdint>
#include <cstddef>

#define DIMC 768
#define NHH  12
#define NSEQ 1024
#define HD   64

#define SX  6291456   // x elems (8*1024*768)
#define SW1 1769472   // qkv_w elems
#define SW2 589824    // proj_w elems

#define RELN 3969     // 63*63 table entries per head
#define RELP 4032     // padded stride

typedef _Float16 f16x8 __attribute__((ext_vector_type(8)));
typedef _Float16 f16x4 __attribute__((ext_vector_type(4)));
typedef float    f32x4 __attribute__((ext_vector_type(4)));
typedef float    f32x16 __attribute__((ext_vector_type(16)));
typedef float    f32x4u __attribute__((ext_vector_type(4), aligned(4)));  // 4B-aligned gather

__device__ inline void gld16(const _Float16* g, _Float16* l) {
  __builtin_amdgcn_global_load_lds(
      (const __attribute__((address_space(1))) void*)g,
      (__attribute__((address_space(3))) void*)l, 16, 0, 0);
}

// ---------------------------------------------------------------------------
// Fused fp32 -> fp16 cast of x | qkv_w | proj_w into one contiguous ws region.
// ---------------------------------------------------------------------------
__global__ __launch_bounds__(256) void cast_f16(
    const float* __restrict__ x, const float* __restrict__ w1,
    const float* __restrict__ w2, _Float16* __restrict__ dst) {
  const long long t = (long long)blockIdx.x * 256 + threadIdx.x;
  const long long i = t * 8;
  const float* src; long long off;
  if (i < SX) { src = x; off = i; }
  else if (i < SX + SW1) { src = w1; off = i - SX; }
  else { src = w2; off = i - (SX + SW1); }
  const float4 a = *(const float4*)(src + off);
  const float4 b = *(const float4*)(src + off + 4);
  f16x8 o;
  o[0] = (_Float16)a.x; o[1] = (_Float16)a.y; o[2] = (_Float16)a.z; o[3] = (_Float16)a.w;
  o[4] = (_Float16)b.x; o[5] = (_Float16)b.y; o[6] = (_Float16)b.z; o[7] = (_Float16)b.w;
  *(f16x8*)(dst + i) = o;
}

// ---------------------------------------------------------------------------
// MFMA GEMM: C[m,o] = sum_k A[m,k]*W[o,k].  128x128 tile, BK=32, m97 structure.
// 1-D grid, XCD-swizzled: m_idx = n & 63 (64 = 0 mod 8 -> same-A-panel blocks
// share an XCD; A is HBM-fetched once, L2-served).
// EPI==0: scatter f16 Q(+bias,*0.125)->[B,NH,N,hd], K->[B,NH,N,hd],
//         V(+bias)->Vt[B,NH,hd,N] (transposed write; vtrans kernel fused away)
// EPI==1: fp32 outF[m*768+o] = acc + b0[o]
// ---------------------------------------------------------------------------
template <int EPI>
__global__ __launch_bounds__(256) void gemm_mfma(
    const _Float16* __restrict__ A, const _Float16* __restrict__ W,
    const float* __restrict__ b0, const float* __restrict__ b1,
    float* __restrict__ outF, _Float16* __restrict__ oq,
    _Float16* __restrict__ ok, _Float16* __restrict__ ovt) {
  __shared__ _Float16 Alds[128 * 32];
  __shared__ _Float16 Blds[128 * 32];

  const int tid = threadIdx.x;
  const int w = tid >> 6, lane = tid & 63, quad = lane >> 4, l16 = lane & 15;
  const int m0 = (blockIdx.x & 63) << 7;
  const int o0 = (blockIdx.x >> 6) << 7;
  const int wr = (w >> 1) * 64, wc = (w & 1) * 64;

  f32x4 acc[4][4];
#pragma unroll
  for (int i = 0; i < 4; i++)
#pragma unroll
    for (int j = 0; j < 4; j++) acc[i][j] = (f32x4){0.f, 0.f, 0.f, 0.f};

  const int c0 = tid, c1 = 256 + tid;
  const int r0 = c0 >> 2, cb0 = (c0 & 3) * 8;
  const int r1 = c1 >> 2, cb1 = (c1 & 3) * 8;
  const _Float16* Ap0 = A + (size_t)(m0 + r0) * DIMC + cb0;
  const _Float16* Ap1 = A + (size_t)(m0 + r1) * DIMC + cb1;
  const _Float16* Wp0 = W + (size_t)(o0 + r0) * DIMC + cb0;
  const _Float16* Wp1 = W + (size_t)(o0 + r1) * DIMC + cb1;

  for (int k0 = 0; k0 < DIMC; k0 += 32) {
    __syncthreads();
    gld16(Ap0 + k0, &Alds[c0 * 8]);
    gld16(Ap1 + k0, &Alds[c1 * 8]);
    gld16(Wp0 + k0, &Blds[c0 * 8]);
    gld16(Wp1 + k0, &Blds[c1 * 8]);
    __syncthreads();

    f16x8 a[4], b[4];
#pragma unroll
    for (int i = 0; i < 4; i++)
      a[i] = *(const f16x8*)&Alds[(wr + i * 16 + l16) * 32 + quad * 8];
#pragma unroll
    for (int j = 0; j < 4; j++)
      b[j] = *(const f16x8*)&Blds[(wc + j * 16 + l16) * 32 + quad * 8];
#pragma unroll
    for (int i = 0; i < 4; i++)
#pragma unroll
      for (int j = 0; j < 4; j++)
        acc[i][j] = __builtin_amdgcn_mfma_f32_16x16x32_f16(a[i], b[j], acc[i][j], 0, 0, 0);
  }

  if constexpr (EPI == 0) {
#pragma unroll
    for (int j = 0; j < 4; j++) {
      const int o = o0 + wc + j * 16 + l16;
      const int part = o / DIMC;
      const int cc = o - part * DIMC;
      const int hh = cc >> 6, d = cc & 63;
      const float badd = (part == 0) ? b0[cc] : (part == 2 ? b1[cc] : 0.f);
      if (part == 2) {
        // V: write transposed into Vt[bh][d][n], f16x4 along n
#pragma unroll
        for (int i = 0; i < 4; i++) {
          const int mb = m0 + wr + i * 16 + quad * 4;
          const int bb = mb >> 10, n0 = mb & 1023;
          f16x4 vv;
#pragma unroll
          for (int r = 0; r < 4; r++) vv[r] = (_Float16)(acc[i][j][r] + badd);
          *(f16x4*)(ovt + (((size_t)(bb * NHH + hh)) * HD + d) * NSEQ + n0) = vv;
        }
      } else {
        _Float16* dst = (part == 0) ? oq : ok;
#pragma unroll
        for (int i = 0; i < 4; i++) {
#pragma unroll
          for (int r = 0; r < 4; r++) {
            const int m = m0 + wr + i * 16 + quad * 4 + r;
            const int bb = m >> 10, n = m & 1023;
            float v = acc[i][j][r];
            if (part == 0) v = (v + badd) * 0.125f;
            dst[(((size_t)(bb * NHH + hh)) * NSEQ + n) * HD + d] = (_Float16)v;
          }
        }
      }
    }
  } else {
#pragma unroll
    for (int j = 0; j < 4; j++) {
      const int o = o0 + wc + j * 16 + l16;
      const float bo = b0[o];
#pragma unroll
      for (int i = 0; i < 4; i++) {
#pragma unroll
        for (int r = 0; r < 4; r++) {
          const int m = m0 + wr + i * 16 + quad * 4 + r;
          outF[(size_t)m * DIMC + o] = acc[i][j][r] + bo;
        }
      }
    }
  }
}

// ---------------------------------------------------------------------------
// Head-major fp32 relative-bias table: relT[h][dy*63+dx] = rel_table[idx][h].
// 190 KB total -> L2-resident, shared by every flash block.
// ---------------------------------------------------------------------------
__global__ __launch_bounds__(256) void relt_pre(const float* __restrict__ rel_table,
                                                float* __restrict__ relT) {
  const int g = blockIdx.x * 256 + threadIdx.x;
  if (g >= NHH * RELN) return;
  const int h = g / RELN, idx = g - h * RELN;
  relT[h * RELP + idx] = rel_table[idx * NHH + h];
}

// ---------------------------------------------------------------------------
// Flash attention, 32x32x16 MFMA transposed compute (S^T = K Q^T, O^T = V^T P^T).
// 1-D grid of 768, bh = n % 96 (96 = 0 mod 8 -> all 8 qt-blocks of one (b,h)
// share an XCD; K/V slice HBM-fetched once, L2-served 8x).
//
// Round 9 changes (latency-bound per rocprof: MfmaUtil 12.5, VALUBusy 25,
// occupancy grid-capped at 3 blk/CU):
//  * T14 async-STAGE split: K/V for kt+1 issued into regs BEFORE compute(kt),
//    ds_written after the next barrier -> HBM/L2 latency hides under MFMA.
//  * bias double-buffer: the 4 relT float4 gathers for tile tau+1 issue at the
//    top of tile tau (~400cy cover) instead of sitting between S-MFMA and exp.
//  * s_setprio(1) around the S and PV MFMA clusters (T5, +4-7% on attn m191).
// ---------------------------------------------------------------------------
__global__ __launch_bounds__(256, 3) void flash_mfma(
    const _Float16* __restrict__ Qg, const _Float16* __restrict__ Kg,
    const _Float16* __restrict__ Vtg, const float* __restrict__ relT,
    _Float16* __restrict__ AO) {
  const int nblk = blockIdx.x;
  const int bhl = nblk % 96;                  // same-XCD group key
  const int qt = nblk / 96;                   // 0..7 (128 q rows each)
  const int head = bhl >> 3, b = bhl & 7;
  const int bh = b * NHH + head;
  const int tid = threadIdx.x, w = tid >> 6, lane = tid & 63;
  const int ql = lane & 31;                   // q column within wave tile
  const int hf = lane >> 5;                   // lane half (k/d sub-offset)

  __shared__ _Float16 Klds[128 * 64];         // [row][chunk^key], 8 chunks/row
  __shared__ _Float16 Vlds[64 * 128];         // [d-row][chunk^key], 16 chunks/row

  // persistent Q B-frags: B[n=ql][k = s*16 + hf*8 + j]
  const int qglob = qt * 128 + w * 32 + ql;
  const _Float16* Qrow = Qg + ((size_t)bh * NSEQ + qglob) * HD + hf * 8;
  f16x8 bq[4];
#pragma unroll
  for (int s = 0; s < 4; s++) bq[s] = *(const f16x8*)(Qrow + s * 16);

  f32x16 O0 = {}, O1 = {};                    // O^T d-tiles 0..31, 32..63
  float psum = 0.f;

  const _Float16* Kbase = Kg + (size_t)bh * NSEQ * HD;
  const _Float16* Vtbase = Vtg + (size_t)bh * HD * NSEQ;

  // bias gather machinery: qy fixed per wave; dy = qy - ky + 31
  const float* relTh = relT + (size_t)head * RELP;
  const int qy = qt * 4 + w;
  const int idxb = ql + 31 - 4 * hf;          // dx = idxb - (r&3) - 8*(r>>2)

  // V A-frag row keys (fixed per lane)
  const int vrow0 = ql, vrow1 = 32 + ql;
  const int vkey0 = (vrow0 ^ (vrow0 >> 3)) & 7;
  const int vkey1 = (vrow1 ^ (vrow1 >> 3)) & 7;

  // ---- staging machinery: per-c4 global offsets + swizzled LDS offsets ----
  int kof[4], vof[4], kpa[4], vpa[4];
#pragma unroll
  for (int c4 = 0; c4 < 4; c4++) {
    const int c = tid + c4 * 256;
    const int kr = c >> 3, kc = c & 7;
    kof[c4] = kr * HD + kc * 8;
    kpa[c4] = (((kr << 3) | (kc ^ ((kr ^ (kr >> 3)) & 7)))) * 8;
    const int vr = c >> 4, vc = c & 15;
    vof[c4] = vr * NSEQ + vc * 8;
    vpa[c4] = (((vr << 4) | (vc ^ ((vr ^ (vr >> 3)) & 7)))) * 8;
  }

  // prologue: issue kt=0 K/V loads into regs
  f16x8 kreg[4], vreg[4];
#pragma unroll
  for (int c4 = 0; c4 < 4; c4++) {
    kreg[c4] = *(const f16x8*)(Kbase + kof[c4]);
    vreg[c4] = *(const f16x8*)(Vtbase + vof[c4]);
  }

  // prologue: bias prefetch for tau=0
  f32x4u bvp[2][4];
  {
    const float* rowb0 = relTh + (qy + 31) * 63 + idxb;
#pragma unroll
    for (int g = 0; g < 4; g++) bvp[0][g] = *(const f32x4u*)(rowb0 - 8 * g - 3);
  }

  for (int kt = 0; kt < 8; kt++) {
    __syncthreads();                          // prev compute done reading LDS
#pragma unroll
    for (int c4 = 0; c4 < 4; c4++) {
      *(f16x8*)&Klds[kpa[c4]] = kreg[c4];
      *(f16x8*)&Vlds[vpa[c4]] = vreg[c4];
    }
    __syncthreads();                          // tile visible to all waves

    if (kt < 7) {                             // issue kt+1 loads; land under compute
#pragma unroll
      for (int c4 = 0; c4 < 4; c4++) {
        kreg[c4] = *(const f16x8*)(Kbase + (kt + 1) * 128 * HD + kof[c4]);
        vreg[c4] = *(const f16x8*)(Vtbase + (kt + 1) * 128 + vof[c4]);
      }
    }

#pragma unroll
    for (int t = 0; t < 4; t++) {
      // bias prefetch for tau+1 (next t, or next kt's t=0).  At the very last
      // tile (tau=31) this reads ~360B below relT -> inside Vt (mapped,
      // discarded) -- safe.
      {
        const int taun = 4 * kt + t + 1;
        const float* rowbn = relTh + (qy + 31 - taun) * 63 + idxb;
#pragma unroll
        for (int g = 0; g < 4; g++)
          bvp[(t + 1) & 1][g] = *(const f32x4u*)(rowbn - 8 * g - 3);
      }

      // S^T 32x32 tile: A = K rows (t*32+ql), contraction d (64)
      const int arow = t * 32 + ql;
      const int akey = (arow ^ (arow >> 3)) & 7;
      f32x16 S = {};
      __builtin_amdgcn_s_setprio(1);
#pragma unroll
      for (int s = 0; s < 4; s++) {
        const f16x8 ak = *(const f16x8*)&Klds[((arow << 3) | ((s * 2 + hf) ^ akey)) * 8];
        S = __builtin_amdgcn_mfma_f32_32x32x16_f16(ak, bq[s], S, 0, 0, 0);
      }
      __builtin_amdgcn_s_setprio(0);

      // bias (prefetched) + exp + psum, pack f16 pairs
      unsigned int dw[8];
#pragma unroll
      for (int g = 0; g < 4; g++) {
        const f32x4u bv = bvp[t & 1][g];      // [j=3,2,1,0]
        const float p0 = __expf(S[4 * g + 0] + bv[3]);
        const float p1 = __expf(S[4 * g + 1] + bv[2]);
        const float p2 = __expf(S[4 * g + 2] + bv[1]);
        const float p3 = __expf(S[4 * g + 3] + bv[0]);
        psum += (p0 + p1) + (p2 + p3);
        union { f16x4 h; unsigned int u[2]; } cv;
        cv.h[0] = (_Float16)p0; cv.h[1] = (_Float16)p1;
        cv.h[2] = (_Float16)p2; cv.h[3] = (_Float16)p3;
        dw[2 * g] = cv.u[0]; dw[2 * g + 1] = cv.u[1];
      }

      // PV: B-frag from P^T via half-exchange; A = V^T rows from LDS
      __builtin_amdgcn_s_setprio(1);
#pragma unroll
      for (int s = 0; s < 2; s++) {
        const unsigned int x0 = hf ? dw[4 * s + 0] : dw[4 * s + 2];
        const unsigned int x1 = hf ? dw[4 * s + 1] : dw[4 * s + 3];
        const unsigned int y0 = (unsigned int)__shfl_xor((int)x0, 32, 64);
        const unsigned int y1 = (unsigned int)__shfl_xor((int)x1, 32, 64);
        union { unsigned int u[4]; f16x8 v; } bp;
        if (hf == 0) {
          bp.u[0] = dw[4 * s + 0]; bp.u[1] = dw[4 * s + 1];
          bp.u[2] = y0;            bp.u[3] = y1;
        } else {
          bp.u[0] = y0;            bp.u[1] = y1;
          bp.u[2] = dw[4 * s + 2]; bp.u[3] = dw[4 * s + 3];
        }
        const int kchunk = t * 4 + s * 2 + hf;
        const f16x8 av0 = *(const f16x8*)&Vlds[((vrow0 << 4) | (kchunk ^ vkey0)) * 8];
        O0 = __builtin_amdgcn_mfma_f32_32x32x16_f16(av0, bp.v, O0, 0, 0, 0);
        const f16x8 av1 = *(const f16x8*)&Vlds[((vrow1 << 4) | (kchunk ^ vkey1)) * 8];
        O1 = __builtin_amdgcn_mfma_f32_32x32x16_f16(av1, bp.v, O1, 0, 0, 0);
      }
      __builtin_amdgcn_s_setprio(0);
    }
  }

  // total row-sum for this lane's q column; divide + store O^T
  psum += __shfl_xor(psum, 32, 64);
  const float inv = 1.f / psum;
  _Float16* aoRow = AO + ((size_t)(b * NSEQ + qglob)) * DIMC + head * HD;
#pragma unroll
  for (int g = 0; g < 4; g++) {
    f16x4 o0, o1;
#pragma unroll
    for (int j = 0; j < 4; j++) {
      o0[j] = (_Float16)(O0[4 * g + j] * inv);
      o1[j] = (_Float16)(O1[4 * g + j] * inv);
    }
    const int d0 = 8 * g + 4 * hf;
    *(f16x4*)(aoRow + d0) = o0;
    *(f16x4*)(aoRow + 32 + d0) = o1;
  }
}

extern "C" void kernel_launch(void* const* d_in, const int* in_sizes, int n_in,
                              void* d_out, int out_size, void* d_ws, size_t ws_size,
                              hipStream_t stream) {
  const float* x        = (const float*)d_in[0];
  const float* qkv_w    = (const float*)d_in[1];
  const float* q_bias   = (const float*)d_in[2];
  const float* v_bias   = (const float*)d_in[3];
  const float* proj_w   = (const float*)d_in[4];
  const float* proj_b   = (const float*)d_in[5];
  const float* rel_tab  = (const float*)d_in[6];
  float* out = (float*)d_out;

  const size_t NTOK = (size_t)8 * NHH * NSEQ * HD;
  _Float16* Xb     = (_Float16*)d_ws;
  _Float16* Wqkvb  = Xb + SX;
  _Float16* Wprojb = Wqkvb + SW1;
  _Float16* Qb     = Wprojb + SW2;
  _Float16* Kb     = Qb + NTOK;
  _Float16* Vt     = Kb + NTOK;             // V written transposed by qkv gemm
  float*    relT   = (float*)(Vt + NTOK);   // 12*4032 fp32 = 193 KB
  _Float16* AOb    = Xb;                    // alias: x consumed before flash writes

  cast_f16<<<dim3((SX + SW1 + SW2) / 2048), 256, 0, stream>>>(x, qkv_w, proj_w, Xb);

  relt_pre<<<dim3((NHH * RELN + 255) / 256), 256, 0, stream>>>(rel_tab, relT);

  gemm_mfma<0><<<dim3(64 * 18), 256, 0, stream>>>(
      Xb, Wqkvb, q_bias, v_bias, nullptr, Qb, Kb, Vt);

  flash_mfma<<<dim3(768), 256, 0, stream>>>(Qb, Kb, Vt, relT, AOb);

  gemm_mfma<1><<<dim3(64 * 6), 256, 0, stream>>>(
      AOb, Wprojb, proj_b, nullptr, out, nullptr, nullptr, nullptr);
}

// Round 2
// 222.814 us; speedup vs baseline: 1.4672x; 1.4672x over previous
//
#include <hip/hip_runtime.h>
#include <cstdint>
#include <cstddef>

#define DIMC 768
#define NHH  12
#define NSEQ 1024
#define HD   64

#define SX  6291456   // x elems (8*1024*768)
#define SW1 1769472   // qkv_w elems
#define SW2 589824    // proj_w elems

#define RELN 3969     // 63*63 table entries per head
#define RELP 4032     // padded stride

typedef _Float16 f16x8 __attribute__((ext_vector_type(8)));
typedef _Float16 f16x4 __attribute__((ext_vector_type(4)));
typedef float    f32x4 __attribute__((ext_vector_type(4)));
typedef float    f32x16 __attribute__((ext_vector_type(16)));
typedef float    f32x4u __attribute__((ext_vector_type(4), aligned(4)));  // 4B-aligned gather

__device__ inline void gld16(const _Float16* g, _Float16* l) {
  __builtin_amdgcn_global_load_lds(
      (const __attribute__((address_space(1))) void*)g,
      (__attribute__((address_space(3))) void*)l, 16, 0, 0);
}

// ---------------------------------------------------------------------------
// Fused fp32 -> fp16 cast of x | qkv_w | proj_w into one contiguous ws region.
// ---------------------------------------------------------------------------
__global__ __launch_bounds__(256) void cast_f16(
    const float* __restrict__ x, const float* __restrict__ w1,
    const float* __restrict__ w2, _Float16* __restrict__ dst) {
  const long long t = (long long)blockIdx.x * 256 + threadIdx.x;
  const long long i = t * 8;
  const float* src; long long off;
  if (i < SX) { src = x; off = i; }
  else if (i < SX + SW1) { src = w1; off = i - SX; }
  else { src = w2; off = i - (SX + SW1); }
  const float4 a = *(const float4*)(src + off);
  const float4 b = *(const float4*)(src + off + 4);
  f16x8 o;
  o[0] = (_Float16)a.x; o[1] = (_Float16)a.y; o[2] = (_Float16)a.z; o[3] = (_Float16)a.w;
  o[4] = (_Float16)b.x; o[5] = (_Float16)b.y; o[6] = (_Float16)b.z; o[7] = (_Float16)b.w;
  *(f16x8*)(dst + i) = o;
}

// ---------------------------------------------------------------------------
// MFMA GEMM: C[m,o] = sum_k A[m,k]*W[o,k].  128x128 tile, BK=32, m97 structure.
// 1-D grid, XCD-swizzled: m_idx = n & 63 (64 = 0 mod 8 -> same-A-panel blocks
// share an XCD; A is HBM-fetched once, L2-served).
// EPI==0: scatter f16 Q(+bias,*0.125)->[B,NH,N,hd], K->[B,NH,N,hd],
//         V(+bias)->Vt[B,NH,hd,N] (transposed write; vtrans kernel fused away)
// EPI==1: fp32 outF[m*768+o] = acc + b0[o]
// ---------------------------------------------------------------------------
template <int EPI>
__global__ __launch_bounds__(256) void gemm_mfma(
    const _Float16* __restrict__ A, const _Float16* __restrict__ W,
    const float* __restrict__ b0, const float* __restrict__ b1,
    float* __restrict__ outF, _Float16* __restrict__ oq,
    _Float16* __restrict__ ok, _Float16* __restrict__ ovt) {
  __shared__ _Float16 Alds[128 * 32];
  __shared__ _Float16 Blds[128 * 32];

  const int tid = threadIdx.x;
  const int w = tid >> 6, lane = tid & 63, quad = lane >> 4, l16 = lane & 15;
  const int m0 = (blockIdx.x & 63) << 7;
  const int o0 = (blockIdx.x >> 6) << 7;
  const int wr = (w >> 1) * 64, wc = (w & 1) * 64;

  f32x4 acc[4][4];
#pragma unroll
  for (int i = 0; i < 4; i++)
#pragma unroll
    for (int j = 0; j < 4; j++) acc[i][j] = (f32x4){0.f, 0.f, 0.f, 0.f};

  const int c0 = tid, c1 = 256 + tid;
  const int r0 = c0 >> 2, cb0 = (c0 & 3) * 8;
  const int r1 = c1 >> 2, cb1 = (c1 & 3) * 8;
  const _Float16* Ap0 = A + (size_t)(m0 + r0) * DIMC + cb0;
  const _Float16* Ap1 = A + (size_t)(m0 + r1) * DIMC + cb1;
  const _Float16* Wp0 = W + (size_t)(o0 + r0) * DIMC + cb0;
  const _Float16* Wp1 = W + (size_t)(o0 + r1) * DIMC + cb1;

  for (int k0 = 0; k0 < DIMC; k0 += 32) {
    __syncthreads();
    gld16(Ap0 + k0, &Alds[c0 * 8]);
    gld16(Ap1 + k0, &Alds[c1 * 8]);
    gld16(Wp0 + k0, &Blds[c0 * 8]);
    gld16(Wp1 + k0, &Blds[c1 * 8]);
    __syncthreads();

    f16x8 a[4], b[4];
#pragma unroll
    for (int i = 0; i < 4; i++)
      a[i] = *(const f16x8*)&Alds[(wr + i * 16 + l16) * 32 + quad * 8];
#pragma unroll
    for (int j = 0; j < 4; j++)
      b[j] = *(const f16x8*)&Blds[(wc + j * 16 + l16) * 32 + quad * 8];
#pragma unroll
    for (int i = 0; i < 4; i++)
#pragma unroll
      for (int j = 0; j < 4; j++)
        acc[i][j] = __builtin_amdgcn_mfma_f32_16x16x32_f16(a[i], b[j], acc[i][j], 0, 0, 0);
  }

  if constexpr (EPI == 0) {
#pragma unroll
    for (int j = 0; j < 4; j++) {
      const int o = o0 + wc + j * 16 + l16;
      const int part = o / DIMC;
      const int cc = o - part * DIMC;
      const int hh = cc >> 6, d = cc & 63;
      const float badd = (part == 0) ? b0[cc] : (part == 2 ? b1[cc] : 0.f);
      if (part == 2) {
        // V: write transposed into Vt[bh][d][n], f16x4 along n
#pragma unroll
        for (int i = 0; i < 4; i++) {
          const int mb = m0 + wr + i * 16 + quad * 4;
          const int bb = mb >> 10, n0 = mb & 1023;
          f16x4 vv;
#pragma unroll
          for (int r = 0; r < 4; r++) vv[r] = (_Float16)(acc[i][j][r] + badd);
          *(f16x4*)(ovt + (((size_t)(bb * NHH + hh)) * HD + d) * NSEQ + n0) = vv;
        }
      } else {
        _Float16* dst = (part == 0) ? oq : ok;
#pragma unroll
        for (int i = 0; i < 4; i++) {
#pragma unroll
          for (int r = 0; r < 4; r++) {
            const int m = m0 + wr + i * 16 + quad * 4 + r;
            const int bb = m >> 10, n = m & 1023;
            float v = acc[i][j][r];
            if (part == 0) v = (v + badd) * 0.125f;
            dst[(((size_t)(bb * NHH + hh)) * NSEQ + n) * HD + d] = (_Float16)v;
          }
        }
      }
    }
  } else {
#pragma unroll
    for (int j = 0; j < 4; j++) {
      const int o = o0 + wc + j * 16 + l16;
      const float bo = b0[o];
#pragma unroll
      for (int i = 0; i < 4; i++) {
#pragma unroll
        for (int r = 0; r < 4; r++) {
          const int m = m0 + wr + i * 16 + quad * 4 + r;
          outF[(size_t)m * DIMC + o] = acc[i][j][r] + bo;
        }
      }
    }
  }
}

// ---------------------------------------------------------------------------
// Head-major fp32 relative-bias table: relT[h][dy*63+dx] = rel_table[idx][h].
// 190 KB total -> L2-resident, shared by every flash block.
// ---------------------------------------------------------------------------
__global__ __launch_bounds__(256) void relt_pre(const float* __restrict__ rel_table,
                                                float* __restrict__ relT) {
  const int g = blockIdx.x * 256 + threadIdx.x;
  if (g >= NHH * RELN) return;
  const int h = g / RELN, idx = g - h * RELN;
  relT[h * RELP + idx] = rel_table[idx * NHH + h];
}

// ---------------------------------------------------------------------------
// Flash attention, 32x32x16 MFMA transposed compute (S^T = K Q^T, O^T = V^T P^T).
// 1-D grid of 768, bh = n % 96 (96 = 0 mod 8 -> all 8 qt-blocks of one (b,h)
// share an XCD; K/V slice HBM-fetched once, L2-served 8x).
//
// Round 10 (post-mortem of r9 spill: +64 live VGPRs across barriers ->
// scratch, FETCH/WRITE x10):
//  * staging via global_load_lds (zero registers, no ds_write VALU):
//    INVERSE-swizzled per-lane global source + LINEAR LDS dest (m173 / rule
//    #21 pattern) reproduces the XOR-swizzled layout bit-exactly; swizzled
//    read side unchanged.  Chunk permutation is within 128B rows -> wave
//    footprint still contiguous 1KB, coalescing intact.
//  * s_setprio(1) around S and PV MFMA clusters (T5; 3 blocks/CU at
//    independent phases gives the scheduler something to arbitrate).
//  * NO reg prefetch, NO bias double-buffer (those caused the r9 spill).
// ---------------------------------------------------------------------------
__global__ __launch_bounds__(256, 3) void flash_mfma(
    const _Float16* __restrict__ Qg, const _Float16* __restrict__ Kg,
    const _Float16* __restrict__ Vtg, const float* __restrict__ relT,
    _Float16* __restrict__ AO) {
  const int nblk = blockIdx.x;
  const int bhl = nblk % 96;                  // same-XCD group key
  const int qt = nblk / 96;                   // 0..7 (128 q rows each)
  const int head = bhl >> 3, b = bhl & 7;
  const int bh = b * NHH + head;
  const int tid = threadIdx.x, w = tid >> 6, lane = tid & 63;
  const int ql = lane & 31;                   // q column within wave tile
  const int hf = lane >> 5;                   // lane half (k/d sub-offset)

  __shared__ _Float16 Klds[128 * 64];         // [row][chunk^key], 8 chunks/row
  __shared__ _Float16 Vlds[64 * 128];         // [d-row][chunk^key], 16 chunks/row

  // persistent Q B-frags: B[n=ql][k = s*16 + hf*8 + j]
  const int qglob = qt * 128 + w * 32 + ql;
  const _Float16* Qrow = Qg + ((size_t)bh * NSEQ + qglob) * HD + hf * 8;
  f16x8 bq[4];
#pragma unroll
  for (int s = 0; s < 4; s++) bq[s] = *(const f16x8*)(Qrow + s * 16);

  f32x16 O0 = {}, O1 = {};                    // O^T d-tiles 0..31, 32..63
  float psum = 0.f;

  const _Float16* Kbase = Kg + (size_t)bh * NSEQ * HD;
  const _Float16* Vtbase = Vtg + (size_t)bh * HD * NSEQ;

  // bias gather machinery: qy fixed per wave; dy = qy - ky + 31
  const float* relTh = relT + (size_t)head * RELP;
  const int qy = qt * 4 + w;
  const int idxb = ql + 31 - 4 * hf;          // dx = idxb - (r&3) - 8*(r>>2)

  // V A-frag row keys (fixed per lane)
  const int vrow0 = ql, vrow1 = 32 + ql;
  const int vkey0 = (vrow0 ^ (vrow0 >> 3)) & 7;
  const int vkey1 = (vrow1 ^ (vrow1 >> 3)) & 7;

  // staging: per-c4 INVERSE-swizzled global source offsets, linear LDS dest.
  // LDS slot c = (kr<<3)|kcL must hold global chunk (kr, kcL ^ key(kr));
  // involution => read side identical to the r8 reg-staged layout.
  int ksrc[4], vsrc[4];
#pragma unroll
  for (int c4 = 0; c4 < 4; c4++) {
    const int c = tid + c4 * 256;
    const int kr = c >> 3, kcL = c & 7;
    const int kkey = (kr ^ (kr >> 3)) & 7;
    ksrc[c4] = kr * HD + (kcL ^ kkey) * 8;
    const int vr = c >> 4, vcL = c & 15;
    const int vkey = (vr ^ (vr >> 3)) & 7;
    vsrc[c4] = vr * NSEQ + (vcL ^ vkey) * 8;
  }

  for (int kt = 0; kt < 8; kt++) {
    __syncthreads();                          // prev compute done reading LDS
#pragma unroll
    for (int c4 = 0; c4 < 4; c4++) {
      const int c = tid + c4 * 256;
      gld16(Kbase + (size_t)kt * 128 * HD + ksrc[c4], &Klds[c * 8]);
      gld16(Vtbase + kt * 128 + vsrc[c4], &Vlds[c * 8]);
    }
    __syncthreads();                          // vmcnt drained -> tile visible

#pragma unroll
    for (int t = 0; t < 4; t++) {
      // S^T 32x32 tile: A = K rows (t*32+ql), contraction d (64)
      const int arow = t * 32 + ql;
      const int akey = (arow ^ (arow >> 3)) & 7;
      f32x16 S = {};
      __builtin_amdgcn_s_setprio(1);
#pragma unroll
      for (int s = 0; s < 4; s++) {
        const f16x8 ak = *(const f16x8*)&Klds[((arow << 3) | ((s * 2 + hf) ^ akey)) * 8];
        S = __builtin_amdgcn_mfma_f32_32x32x16_f16(ak, bq[s], S, 0, 0, 0);
      }
      __builtin_amdgcn_s_setprio(0);

      // bias via float4 gathers (row is L1/L2-hot) + exp + psum, pack f16
      const float* rowb = relTh + (qy - (kt * 4 + t) + 31) * 63 + idxb;
      unsigned int dw[8];
#pragma unroll
      for (int g = 0; g < 4; g++) {
        const f32x4u bv = *(const f32x4u*)(rowb - 8 * g - 3);  // [j=3,2,1,0]
        const float p0 = __expf(S[4 * g + 0] + bv[3]);
        const float p1 = __expf(S[4 * g + 1] + bv[2]);
        const float p2 = __expf(S[4 * g + 2] + bv[1]);
        const float p3 = __expf(S[4 * g + 3] + bv[0]);
        psum += (p0 + p1) + (p2 + p3);
        union { f16x4 h; unsigned int u[2]; } cv;
        cv.h[0] = (_Float16)p0; cv.h[1] = (_Float16)p1;
        cv.h[2] = (_Float16)p2; cv.h[3] = (_Float16)p3;
        dw[2 * g] = cv.u[0]; dw[2 * g + 1] = cv.u[1];
      }

      // PV: B-frag from P^T via half-exchange; A = V^T rows from LDS
      __builtin_amdgcn_s_setprio(1);
#pragma unroll
      for (int s = 0; s < 2; s++) {
        const unsigned int x0 = hf ? dw[4 * s + 0] : dw[4 * s + 2];
        const unsigned int x1 = hf ? dw[4 * s + 1] : dw[4 * s + 3];
        const unsigned int y0 = (unsigned int)__shfl_xor((int)x0, 32, 64);
        const unsigned int y1 = (unsigned int)__shfl_xor((int)x1, 32, 64);
        union { unsigned int u[4]; f16x8 v; } bp;
        if (hf == 0) {
          bp.u[0] = dw[4 * s + 0]; bp.u[1] = dw[4 * s + 1];
          bp.u[2] = y0;            bp.u[3] = y1;
        } else {
          bp.u[0] = y0;            bp.u[1] = y1;
          bp.u[2] = dw[4 * s + 2]; bp.u[3] = dw[4 * s + 3];
        }
        const int kchunk = t * 4 + s * 2 + hf;
        const f16x8 av0 = *(const f16x8*)&Vlds[((vrow0 << 4) | (kchunk ^ vkey0)) * 8];
        O0 = __builtin_amdgcn_mfma_f32_32x32x16_f16(av0, bp.v, O0, 0, 0, 0);
        const f16x8 av1 = *(const f16x8*)&Vlds[((vrow1 << 4) | (kchunk ^ vkey1)) * 8];
        O1 = __builtin_amdgcn_mfma_f32_32x32x16_f16(av1, bp.v, O1, 0, 0, 0);
      }
      __builtin_amdgcn_s_setprio(0);
    }
  }

  // total row-sum for this lane's q column; divide + store O^T
  psum += __shfl_xor(psum, 32, 64);
  const float inv = 1.f / psum;
  _Float16* aoRow = AO + ((size_t)(b * NSEQ + qglob)) * DIMC + head * HD;
#pragma unroll
  for (int g = 0; g < 4; g++) {
    f16x4 o0, o1;
#pragma unroll
    for (int j = 0; j < 4; j++) {
      o0[j] = (_Float16)(O0[4 * g + j] * inv);
      o1[j] = (_Float16)(O1[4 * g + j] * inv);
    }
    const int d0 = 8 * g + 4 * hf;
    *(f16x4*)(aoRow + d0) = o0;
    *(f16x4*)(aoRow + 32 + d0) = o1;
  }
}

extern "C" void kernel_launch(void* const* d_in, const int* in_sizes, int n_in,
                              void* d_out, int out_size, void* d_ws, size_t ws_size,
                              hipStream_t stream) {
  const float* x        = (const float*)d_in[0];
  const float* qkv_w    = (const float*)d_in[1];
  const float* q_bias   = (const float*)d_in[2];
  const float* v_bias   = (const float*)d_in[3];
  const float* proj_w   = (const float*)d_in[4];
  const float* proj_b   = (const float*)d_in[5];
  const float* rel_tab  = (const float*)d_in[6];
  float* out = (float*)d_out;

  const size_t NTOK = (size_t)8 * NHH * NSEQ * HD;
  _Float16* Xb     = (_Float16*)d_ws;
  _Float16* Wqkvb  = Xb + SX;
  _Float16* Wprojb = Wqkvb + SW1;
  _Float16* Qb     = Wprojb + SW2;
  _Float16* Kb     = Qb + NTOK;
  _Float16* Vt     = Kb + NTOK;             // V written transposed by qkv gemm
  float*    relT   = (float*)(Vt + NTOK);   // 12*4032 fp32 = 193 KB
  _Float16* AOb    = Xb;                    // alias: x consumed before flash writes

  cast_f16<<<dim3((SX + SW1 + SW2) / 2048), 256, 0, stream>>>(x, qkv_w, proj_w, Xb);

  relt_pre<<<dim3((NHH * RELN + 255) / 256), 256, 0, stream>>>(rel_tab, relT);

  gemm_mfma<0><<<dim3(64 * 18), 256, 0, stream>>>(
      Xb, Wqkvb, q_bias, v_bias, nullptr, Qb, Kb, Vt);

  flash_mfma<<<dim3(768), 256, 0, stream>>>(Qb, Kb, Vt, relT, AOb);

  gemm_mfma<1><<<dim3(64 * 6), 256, 0, stream>>>(
      AOb, Wprojb, proj_b, nullptr, out, nullptr, nullptr, nullptr);
}

// Round 3
// 210.979 us; speedup vs baseline: 1.5496x; 1.0561x over previous
//
#include <hip/hip_runtime.h>
#include <cstdint>
#include <cstddef>

#define DIMC 768
#define NHH  12
#define NSEQ 1024
#define HD   64

#define SX  6291456   // x elems (8*1024*768)
#define SW1 1769472   // qkv_w elems
#define SW2 589824    // proj_w elems

#define RELN 3969     // 63*63 table entries per head
#define RELP 4032     // padded stride

typedef _Float16 f16x8 __attribute__((ext_vector_type(8)));
typedef _Float16 f16x4 __attribute__((ext_vector_type(4)));
typedef float    f32x4 __attribute__((ext_vector_type(4)));
typedef float    f32x16 __attribute__((ext_vector_type(16)));

__device__ inline void gld16(const void* g, void* l) {
  __builtin_amdgcn_global_load_lds(
      (const __attribute__((address_space(1))) void*)g,
      (__attribute__((address_space(3))) void*)l, 16, 0, 0);
}

// ---------------------------------------------------------------------------
// Fused fp32 -> fp16 cast of x | qkv_w | proj_w into one contiguous ws region.
// ---------------------------------------------------------------------------
__global__ __launch_bounds__(256) void cast_f16(
    const float* __restrict__ x, const float* __restrict__ w1,
    const float* __restrict__ w2, _Float16* __restrict__ dst) {
  const long long t = (long long)blockIdx.x * 256 + threadIdx.x;
  const long long i = t * 8;
  const float* src; long long off;
  if (i < SX) { src = x; off = i; }
  else if (i < SX + SW1) { src = w1; off = i - SX; }
  else { src = w2; off = i - (SX + SW1); }
  const float4 a = *(const float4*)(src + off);
  const float4 b = *(const float4*)(src + off + 4);
  f16x8 o;
  o[0] = (_Float16)a.x; o[1] = (_Float16)a.y; o[2] = (_Float16)a.z; o[3] = (_Float16)a.w;
  o[4] = (_Float16)b.x; o[5] = (_Float16)b.y; o[6] = (_Float16)b.z; o[7] = (_Float16)b.w;
  *(f16x8*)(dst + i) = o;
}

// ---------------------------------------------------------------------------
// MFMA GEMM: C[m,o] = sum_k A[m,k]*W[o,k].  128x128 tile, BK=32, m97 structure.
// 1-D grid, XCD-swizzled: m_idx = n & 63 (64 = 0 mod 8 -> same-A-panel blocks
// share an XCD; A is HBM-fetched once, L2-served).
// EPI==0: scatter f16 Q(+bias,*0.125)->[B,NH,N,hd], K->[B,NH,N,hd],
//         V(+bias)->Vt[B,NH,hd,N] (transposed write; vtrans kernel fused away)
// EPI==1: fp32 outF[m*768+o] = acc + b0[o]
// ---------------------------------------------------------------------------
template <int EPI>
__global__ __launch_bounds__(256) void gemm_mfma(
    const _Float16* __restrict__ A, const _Float16* __restrict__ W,
    const float* __restrict__ b0, const float* __restrict__ b1,
    float* __restrict__ outF, _Float16* __restrict__ oq,
    _Float16* __restrict__ ok, _Float16* __restrict__ ovt) {
  __shared__ _Float16 Alds[128 * 32];
  __shared__ _Float16 Blds[128 * 32];

  const int tid = threadIdx.x;
  const int w = tid >> 6, lane = tid & 63, quad = lane >> 4, l16 = lane & 15;
  const int m0 = (blockIdx.x & 63) << 7;
  const int o0 = (blockIdx.x >> 6) << 7;
  const int wr = (w >> 1) * 64, wc = (w & 1) * 64;

  f32x4 acc[4][4];
#pragma unroll
  for (int i = 0; i < 4; i++)
#pragma unroll
    for (int j = 0; j < 4; j++) acc[i][j] = (f32x4){0.f, 0.f, 0.f, 0.f};

  const int c0 = tid, c1 = 256 + tid;
  const int r0 = c0 >> 2, cb0 = (c0 & 3) * 8;
  const int r1 = c1 >> 2, cb1 = (c1 & 3) * 8;
  const _Float16* Ap0 = A + (size_t)(m0 + r0) * DIMC + cb0;
  const _Float16* Ap1 = A + (size_t)(m0 + r1) * DIMC + cb1;
  const _Float16* Wp0 = W + (size_t)(o0 + r0) * DIMC + cb0;
  const _Float16* Wp1 = W + (size_t)(o0 + r1) * DIMC + cb1;

  for (int k0 = 0; k0 < DIMC; k0 += 32) {
    __syncthreads();
    gld16(Ap0 + k0, &Alds[c0 * 8]);
    gld16(Ap1 + k0, &Alds[c1 * 8]);
    gld16(Wp0 + k0, &Blds[c0 * 8]);
    gld16(Wp1 + k0, &Blds[c1 * 8]);
    __syncthreads();

    f16x8 a[4], b[4];
#pragma unroll
    for (int i = 0; i < 4; i++)
      a[i] = *(const f16x8*)&Alds[(wr + i * 16 + l16) * 32 + quad * 8];
#pragma unroll
    for (int j = 0; j < 4; j++)
      b[j] = *(const f16x8*)&Blds[(wc + j * 16 + l16) * 32 + quad * 8];
#pragma unroll
    for (int i = 0; i < 4; i++)
#pragma unroll
      for (int j = 0; j < 4; j++)
        acc[i][j] = __builtin_amdgcn_mfma_f32_16x16x32_f16(a[i], b[j], acc[i][j], 0, 0, 0);
  }

  if constexpr (EPI == 0) {
#pragma unroll
    for (int j = 0; j < 4; j++) {
      const int o = o0 + wc + j * 16 + l16;
      const int part = o / DIMC;
      const int cc = o - part * DIMC;
      const int hh = cc >> 6, d = cc & 63;
      const float badd = (part == 0) ? b0[cc] : (part == 2 ? b1[cc] : 0.f);
      if (part == 2) {
        // V: write transposed into Vt[bh][d][n], f16x4 along n
#pragma unroll
        for (int i = 0; i < 4; i++) {
          const int mb = m0 + wr + i * 16 + quad * 4;
          const int bb = mb >> 10, n0 = mb & 1023;
          f16x4 vv;
#pragma unroll
          for (int r = 0; r < 4; r++) vv[r] = (_Float16)(acc[i][j][r] + badd);
          *(f16x4*)(ovt + (((size_t)(bb * NHH + hh)) * HD + d) * NSEQ + n0) = vv;
        }
      } else {
        _Float16* dst = (part == 0) ? oq : ok;
#pragma unroll
        for (int i = 0; i < 4; i++) {
#pragma unroll
          for (int r = 0; r < 4; r++) {
            const int m = m0 + wr + i * 16 + quad * 4 + r;
            const int bb = m >> 10, n = m & 1023;
            float v = acc[i][j][r];
            if (part == 0) v = (v + badd) * 0.125f;
            dst[(((size_t)(bb * NHH + hh)) * NSEQ + n) * HD + d] = (_Float16)v;
          }
        }
      }
    }
  } else {
#pragma unroll
    for (int j = 0; j < 4; j++) {
      const int o = o0 + wc + j * 16 + l16;
      const float bo = b0[o];
#pragma unroll
      for (int i = 0; i < 4; i++) {
#pragma unroll
        for (int r = 0; r < 4; r++) {
          const int m = m0 + wr + i * 16 + quad * 4 + r;
          outF[(size_t)m * DIMC + o] = acc[i][j][r] + bo;
        }
      }
    }
  }
}

// ---------------------------------------------------------------------------
// Head-major fp32 relative-bias table: relT[h][dy*63+dx] = rel_table[idx][h].
// 190 KB total -> L2-resident, shared by every flash block.
// ---------------------------------------------------------------------------
__global__ __launch_bounds__(256) void relt_pre(const float* __restrict__ rel_table,
                                                float* __restrict__ relT) {
  const int g = blockIdx.x * 256 + threadIdx.x;
  if (g >= NHH * RELN) return;
  const int h = g / RELN, idx = g - h * RELN;
  relT[h * RELP + idx] = rel_table[idx * NHH + h];
}

// ---------------------------------------------------------------------------
// Flash attention, 32x32x16 MFMA transposed compute (S^T = K Q^T, O^T = V^T P^T).
// 1-D grid of 768, bh = n % 96 (96 = 0 mod 8 -> all 8 qt-blocks of one (b,h)
// share an XCD; K/V slice HBM-fetched once, L2-served 8x).
//
// Round 11 (r10 profile: MfmaUtil 15.8 / VALUBusy 32 -> half the issue slots
// are stalls; two identified causes attacked):
//  * KVBLK=64 + LDS double-buffer, SINGLE barrier per step (T3 2-phase):
//    stage(s+1) via gld_lds -> compute(s) -> [implicit vmcnt(0)] barrier.
//    Load latency rides under ~800cy of compute; LDS stays 32KB (2x16KB)
//    so occupancy is unchanged (m132 trap avoided).
//  * bias rows staged to LDS: the per-step working set is 5 consecutive
//    relT rows = one contiguous 316-float span -> two coalesced gld_lds.
//    Replaces 512 divergent global dword gathers + 64-bit addressing per
//    wave with conflict-free ds_read_b32 (lanes hit consecutive banks).
//  * staging still register-free (inverse-swizzle gld_lds, rule #21).
// ---------------------------------------------------------------------------
__global__ __launch_bounds__(256, 3) void flash_mfma(
    const _Float16* __restrict__ Qg, const _Float16* __restrict__ Kg,
    const _Float16* __restrict__ Vtg, const float* __restrict__ relT,
    _Float16* __restrict__ AO) {
  const int nblk = blockIdx.x;
  const int bhl = nblk % 96;                  // same-XCD group key
  const int qt = nblk / 96;                   // 0..7 (128 q rows each)
  const int head = bhl >> 3, b = bhl & 7;
  const int bh = b * NHH + head;
  const int tid = threadIdx.x, w = tid >> 6, lane = tid & 63;
  const int ql = lane & 31;                   // q column within wave tile
  const int hf = lane >> 5;                   // lane half (k/d sub-offset)

  // double-buffered K/V tiles (KVBLK=64): 2 x (8+8) KB = 32 KB
  __shared__ _Float16 Klds[2][64 * 64];       // [row][chunk^key], 8 chunks/row
  __shared__ _Float16 Vlds[2][64 * 64];       // [d-row][chunk^key], 8 chunks/row
  __shared__ __attribute__((aligned(16))) float BiasLds[2][320];  // 5 rows x 63 + pad

  // persistent Q B-frags: B[n=ql][k = s*16 + hf*8 + j]
  const int qglob = qt * 128 + w * 32 + ql;
  const _Float16* Qrow = Qg + ((size_t)bh * NSEQ + qglob) * HD + hf * 8;
  f16x8 bq[4];
#pragma unroll
  for (int s = 0; s < 4; s++) bq[s] = *(const f16x8*)(Qrow + s * 16);

  f32x16 O0 = {}, O1 = {};                    // O^T d-tiles 0..31, 32..63
  float psum = 0.f;

  const _Float16* Kbase = Kg + (size_t)bh * NSEQ * HD;
  const _Float16* Vtbase = Vtg + (size_t)bh * HD * NSEQ;

  // bias: qy fixed per wave; dy = qy - tau + 31, tau = 2*step + t
  const float* relTh = relT + (size_t)head * RELP;
  const int idxb = ql + 31 - 4 * hf;          // dx = idxb - (r&3) - 8*(r>>2)

  // V A-frag row keys (fixed per lane)
  const int vrow0 = ql, vrow1 = 32 + ql;
  const int vkey0 = (vrow0 ^ (vrow0 >> 3)) & 7;
  const int vkey1 = (vrow1 ^ (vrow1 >> 3)) & 7;

  // staging: inverse-swizzled global offsets, linear LDS dest (involution).
  // K and V share the 64-row x 8-chunk grid -> same (row, chunk, key) pairs.
  int ks0, ks1, vs0, vs1;
  {
    int c = tid;
    int r = c >> 3, cc = c & 7, key = (r ^ (r >> 3)) & 7;
    ks0 = r * HD + (cc ^ key) * 8;
    vs0 = r * NSEQ + (cc ^ key) * 8;
    c = tid + 256;
    r = c >> 3; cc = c & 7; key = (r ^ (r >> 3)) & 7;
    ks1 = r * HD + (cc ^ key) * 8;
    vs1 = r * NSEQ + (cc ^ key) * 8;
  }

  // stage step s into buffer bsel (K 8KB + V 8KB + bias 316 floats)
  auto stage = [&](int s, int bsel) {
    const _Float16* Ks = Kbase + (size_t)s * 64 * HD;
    const _Float16* Vs = Vtbase + s * 64;
    gld16(Ks + ks0, &Klds[bsel][tid * 8]);
    gld16(Ks + ks1, &Klds[bsel][(tid + 256) * 8]);
    gld16(Vs + vs0, &Vlds[bsel][tid * 8]);
    gld16(Vs + vs1, &Vlds[bsel][(tid + 256) * 8]);
    if (tid < 79) {                           // 79*4 = 316 floats, contiguous
      const int dyLo = qt * 4 + 30 - 2 * s;   // in [0, 58]; span <= RELP pad
      gld16(relTh + dyLo * 63 + tid * 4, &BiasLds[bsel][tid * 4]);
    }
  };

  stage(0, 0);                                // prologue (only exposed latency)

  int cur = 0;
#pragma unroll 2
  for (int s = 0; s < 16; s++) {
    __syncthreads();                          // drains own vmcnt -> buf[cur] ready
    if (s + 1 < 16) stage(s + 1, cur ^ 1);    // in flight under compute(s)

#pragma unroll
    for (int t = 0; t < 2; t++) {
      // S^T 32x32 tile: A = K rows (t*32+ql), contraction d (64)
      const int arow = t * 32 + ql;
      const int akey = (arow ^ (arow >> 3)) & 7;
      f32x16 S = {};
      __builtin_amdgcn_s_setprio(1);
#pragma unroll
      for (int ss = 0; ss < 4; ss++) {
        const f16x8 ak = *(const f16x8*)&Klds[cur][((arow << 3) | ((ss * 2 + hf) ^ akey)) * 8];
        S = __builtin_amdgcn_mfma_f32_32x32x16_f16(ak, bq[ss], S, 0, 0, 0);
      }
      __builtin_amdgcn_s_setprio(0);

      // bias from LDS (row = w+1-t, conflict-free lane-consecutive reads)
      // p_j of group g adds relT row entry [idxb - 8g - j]
      const float* lb = &BiasLds[cur][(w + 1 - t) * 63 + idxb];
      unsigned int dw[8];
#pragma unroll
      for (int g = 0; g < 4; g++) {
        const float b0 = lb[-8 * g - 0];
        const float b1 = lb[-8 * g - 1];
        const float b2 = lb[-8 * g - 2];
        const float b3 = lb[-8 * g - 3];
        const float p0 = __expf(S[4 * g + 0] + b0);
        const float p1 = __expf(S[4 * g + 1] + b1);
        const float p2 = __expf(S[4 * g + 2] + b2);
        const float p3 = __expf(S[4 * g + 3] + b3);
        psum += (p0 + p1) + (p2 + p3);
        union { f16x4 h; unsigned int u[2]; } cv;
        cv.h[0] = (_Float16)p0; cv.h[1] = (_Float16)p1;
        cv.h[2] = (_Float16)p2; cv.h[3] = (_Float16)p3;
        dw[2 * g] = cv.u[0]; dw[2 * g + 1] = cv.u[1];
      }

      // PV: B-frag from P^T via half-exchange; A = V^T rows from LDS
      __builtin_amdgcn_s_setprio(1);
#pragma unroll
      for (int s2 = 0; s2 < 2; s2++) {
        const unsigned int x0 = hf ? dw[4 * s2 + 0] : dw[4 * s2 + 2];
        const unsigned int x1 = hf ? dw[4 * s2 + 1] : dw[4 * s2 + 3];
        const unsigned int y0 = (unsigned int)__shfl_xor((int)x0, 32, 64);
        const unsigned int y1 = (unsigned int)__shfl_xor((int)x1, 32, 64);
        union { unsigned int u[4]; f16x8 v; } bp;
        if (hf == 0) {
          bp.u[0] = dw[4 * s2 + 0]; bp.u[1] = dw[4 * s2 + 1];
          bp.u[2] = y0;             bp.u[3] = y1;
        } else {
          bp.u[0] = y0;             bp.u[1] = y1;
          bp.u[2] = dw[4 * s2 + 2]; bp.u[3] = dw[4 * s2 + 3];
        }
        const int kchunk = t * 4 + s2 * 2 + hf;
        const f16x8 av0 = *(const f16x8*)&Vlds[cur][((vrow0 << 3) | (kchunk ^ vkey0)) * 8];
        O0 = __builtin_amdgcn_mfma_f32_32x32x16_f16(av0, bp.v, O0, 0, 0, 0);
        const f16x8 av1 = *(const f16x8*)&Vlds[cur][((vrow1 << 3) | (kchunk ^ vkey1)) * 8];
        O1 = __builtin_amdgcn_mfma_f32_32x32x16_f16(av1, bp.v, O1, 0, 0, 0);
      }
      __builtin_amdgcn_s_setprio(0);
    }
    cur ^= 1;
  }

  // total row-sum for this lane's q column; divide + store O^T
  psum += __shfl_xor(psum, 32, 64);
  const float inv = 1.f / psum;
  _Float16* aoRow = AO + ((size_t)(b * NSEQ + qglob)) * DIMC + head * HD;
#pragma unroll
  for (int g = 0; g < 4; g++) {
    f16x4 o0, o1;
#pragma unroll
    for (int j = 0; j < 4; j++) {
      o0[j] = (_Float16)(O0[4 * g + j] * inv);
      o1[j] = (_Float16)(O1[4 * g + j] * inv);
    }
    const int d0 = 8 * g + 4 * hf;
    *(f16x4*)(aoRow + d0) = o0;
    *(f16x4*)(aoRow + 32 + d0) = o1;
  }
}

extern "C" void kernel_launch(void* const* d_in, const int* in_sizes, int n_in,
                              void* d_out, int out_size, void* d_ws, size_t ws_size,
                              hipStream_t stream) {
  const float* x        = (const float*)d_in[0];
  const float* qkv_w    = (const float*)d_in[1];
  const float* q_bias   = (const float*)d_in[2];
  const float* v_bias   = (const float*)d_in[3];
  const float* proj_w   = (const float*)d_in[4];
  const float* proj_b   = (const float*)d_in[5];
  const float* rel_tab  = (const float*)d_in[6];
  float* out = (float*)d_out;

  const size_t NTOK = (size_t)8 * NHH * NSEQ * HD;
  _Float16* Xb     = (_Float16*)d_ws;
  _Float16* Wqkvb  = Xb + SX;
  _Float16* Wprojb = Wqkvb + SW1;
  _Float16* Qb     = Wprojb + SW2;
  _Float16* Kb     = Qb + NTOK;
  _Float16* Vt     = Kb + NTOK;             // V written transposed by qkv gemm
  float*    relT   = (float*)(Vt + NTOK);   // 12*4032 fp32 = 193 KB
  _Float16* AOb    = Xb;                    // alias: x consumed before flash writes

  cast_f16<<<dim3((SX + SW1 + SW2) / 2048), 256, 0, stream>>>(x, qkv_w, proj_w, Xb);

  relt_pre<<<dim3((NHH * RELN + 255) / 256), 256, 0, stream>>>(rel_tab, relT);

  gemm_mfma<0><<<dim3(64 * 18), 256, 0, stream>>>(
      Xb, Wqkvb, q_bias, v_bias, nullptr, Qb, Kb, Vt);

  flash_mfma<<<dim3(768), 256, 0, stream>>>(Qb, Kb, Vt, relT, AOb);

  gemm_mfma<1><<<dim3(64 * 6), 256, 0, stream>>>(
      AOb, Wprojb, proj_b, nullptr, out, nullptr, nullptr, nullptr);
}

// Round 4
// 205.101 us; speedup vs baseline: 1.5940x; 1.0287x over previous
//
#include <hip/hip_runtime.h>
#include <cstdint>
#include <cstddef>

#define DIMC 768
#define NHH  12
#define NSEQ 1024
#define HD   64

#define SX  6291456   // x elems (8*1024*768)
#define SW1 1769472   // qkv_w elems
#define SW2 589824    // proj_w elems

#define RELN 3969     // 63*63 table entries per head
#define RELP 4032     // padded stride

#define NCAST ((SX + SW1 + SW2) / 2048)       // 4224 cast blocks
#define NRELB ((NHH * RELN + 255) / 256)      // 187 relt blocks

typedef _Float16 f16x8 __attribute__((ext_vector_type(8)));
typedef _Float16 f16x4 __attribute__((ext_vector_type(4)));
typedef float    f32x4 __attribute__((ext_vector_type(4)));
typedef float    f32x16 __attribute__((ext_vector_type(16)));

__device__ inline void gld16(const void* g, void* l) {
  __builtin_amdgcn_global_load_lds(
      (const __attribute__((address_space(1))) void*)g,
      (__attribute__((address_space(3))) void*)l, 16, 0, 0);
}

// ---------------------------------------------------------------------------
// Fused fp32 -> fp16 cast of x | qkv_w | proj_w into one contiguous ws region,
// PLUS (tail blocks) the head-major fp32 relative-bias table transpose:
// relT[h][dy*63+dx] = rel_table[idx][h].  One launch fewer.
// ---------------------------------------------------------------------------
__global__ __launch_bounds__(256) void cast_f16(
    const float* __restrict__ x, const float* __restrict__ w1,
    const float* __restrict__ w2, _Float16* __restrict__ dst,
    const float* __restrict__ rel_table, float* __restrict__ relT) {
  if (blockIdx.x >= NCAST) {                  // relT transpose tail
    const int g = (blockIdx.x - NCAST) * 256 + threadIdx.x;
    if (g < NHH * RELN) {
      const int h = g / RELN, idx = g - h * RELN;
      relT[h * RELP + idx] = rel_table[idx * NHH + h];
    }
    return;
  }
  const long long t = (long long)blockIdx.x * 256 + threadIdx.x;
  const long long i = t * 8;
  const float* src; long long off;
  if (i < SX) { src = x; off = i; }
  else if (i < SX + SW1) { src = w1; off = i - SX; }
  else { src = w2; off = i - (SX + SW1); }
  const float4 a = *(const float4*)(src + off);
  const float4 b = *(const float4*)(src + off + 4);
  f16x8 o;
  o[0] = (_Float16)a.x; o[1] = (_Float16)a.y; o[2] = (_Float16)a.z; o[3] = (_Float16)a.w;
  o[4] = (_Float16)b.x; o[5] = (_Float16)b.y; o[6] = (_Float16)b.z; o[7] = (_Float16)b.w;
  *(f16x8*)(dst + i) = o;
}

// ---------------------------------------------------------------------------
// MFMA GEMM: C[m,o] = sum_k A[m,k]*W[o,k].  128x128 tile, BK=32.
// Round 12: T3 2-phase double-buffer (mirrors the flash r11 win): stage(k+1)
// via gld_lds issued BEFORE compute(k), ONE barrier per K-step.  The implicit
// vmcnt(0)-before-barrier now waits on loads issued a full compute phase ago
// (~300cy covered) instead of draining cold latency inside a double barrier.
// LDS 2x(8+8)KB = 32KB; occupancy unchanged.
// 1-D grid, XCD-swizzled: m_idx = n & 63 (64 = 0 mod 8 -> same-A-panel blocks
// share an XCD; A is HBM-fetched once, L2-served).
// EPI==0: scatter f16 Q(+bias,*0.125)->[B,NH,N,hd], K->[B,NH,N,hd],
//         V(+bias)->Vt[B,NH,hd,N] (transposed write)
// EPI==1: fp32 outF[m*768+o] = acc + b0[o]
// ---------------------------------------------------------------------------
template <int EPI>
__global__ __launch_bounds__(256) void gemm_mfma(
    const _Float16* __restrict__ A, const _Float16* __restrict__ W,
    const float* __restrict__ b0, const float* __restrict__ b1,
    float* __restrict__ outF, _Float16* __restrict__ oq,
    _Float16* __restrict__ ok, _Float16* __restrict__ ovt) {
  __shared__ _Float16 Alds[2][128 * 32];
  __shared__ _Float16 Blds[2][128 * 32];

  const int tid = threadIdx.x;
  const int w = tid >> 6, lane = tid & 63, quad = lane >> 4, l16 = lane & 15;
  const int m0 = (blockIdx.x & 63) << 7;
  const int o0 = (blockIdx.x >> 6) << 7;
  const int wr = (w >> 1) * 64, wc = (w & 1) * 64;

  f32x4 acc[4][4];
#pragma unroll
  for (int i = 0; i < 4; i++)
#pragma unroll
    for (int j = 0; j < 4; j++) acc[i][j] = (f32x4){0.f, 0.f, 0.f, 0.f};

  const int c0 = tid, c1 = 256 + tid;
  const int r0 = c0 >> 2, cb0 = (c0 & 3) * 8;
  const int r1 = c1 >> 2, cb1 = (c1 & 3) * 8;
  const _Float16* Ap0 = A + (size_t)(m0 + r0) * DIMC + cb0;
  const _Float16* Ap1 = A + (size_t)(m0 + r1) * DIMC + cb1;
  const _Float16* Wp0 = W + (size_t)(o0 + r0) * DIMC + cb0;
  const _Float16* Wp1 = W + (size_t)(o0 + r1) * DIMC + cb1;

  auto stage = [&](int k0, int bsel) {
    gld16(Ap0 + k0, &Alds[bsel][c0 * 8]);
    gld16(Ap1 + k0, &Alds[bsel][c1 * 8]);
    gld16(Wp0 + k0, &Blds[bsel][c0 * 8]);
    gld16(Wp1 + k0, &Blds[bsel][c1 * 8]);
  };

  stage(0, 0);                                // prologue: only exposed latency
  int cur = 0;

#pragma unroll 2
  for (int k0 = 0; k0 < DIMC; k0 += 32) {
    __syncthreads();                          // buf[cur] landed; reads of buf[cur^1] done
    if (k0 + 32 < DIMC) stage(k0 + 32, cur ^ 1);   // in flight under compute

    f16x8 a[4], b[4];
#pragma unroll
    for (int i = 0; i < 4; i++)
      a[i] = *(const f16x8*)&Alds[cur][(wr + i * 16 + l16) * 32 + quad * 8];
#pragma unroll
    for (int j = 0; j < 4; j++)
      b[j] = *(const f16x8*)&Blds[cur][(wc + j * 16 + l16) * 32 + quad * 8];
#pragma unroll
    for (int i = 0; i < 4; i++)
#pragma unroll
      for (int j = 0; j < 4; j++)
        acc[i][j] = __builtin_amdgcn_mfma_f32_16x16x32_f16(a[i], b[j], acc[i][j], 0, 0, 0);
    cur ^= 1;
  }

  if constexpr (EPI == 0) {
#pragma unroll
    for (int j = 0; j < 4; j++) {
      const int o = o0 + wc + j * 16 + l16;
      const int part = o / DIMC;
      const int cc = o - part * DIMC;
      const int hh = cc >> 6, d = cc & 63;
      const float badd = (part == 0) ? b0[cc] : (part == 2 ? b1[cc] : 0.f);
      if (part == 2) {
        // V: write transposed into Vt[bh][d][n], f16x4 along n
#pragma unroll
        for (int i = 0; i < 4; i++) {
          const int mb = m0 + wr + i * 16 + quad * 4;
          const int bb = mb >> 10, n0 = mb & 1023;
          f16x4 vv;
#pragma unroll
          for (int r = 0; r < 4; r++) vv[r] = (_Float16)(acc[i][j][r] + badd);
          *(f16x4*)(ovt + (((size_t)(bb * NHH + hh)) * HD + d) * NSEQ + n0) = vv;
        }
      } else {
        _Float16* dst = (part == 0) ? oq : ok;
#pragma unroll
        for (int i = 0; i < 4; i++) {
#pragma unroll
          for (int r = 0; r < 4; r++) {
            const int m = m0 + wr + i * 16 + quad * 4 + r;
            const int bb = m >> 10, n = m & 1023;
            float v = acc[i][j][r];
            if (part == 0) v = (v + badd) * 0.125f;
            dst[(((size_t)(bb * NHH + hh)) * NSEQ + n) * HD + d] = (_Float16)v;
          }
        }
      }
    }
  } else {
#pragma unroll
    for (int j = 0; j < 4; j++) {
      const int o = o0 + wc + j * 16 + l16;
      const float bo = b0[o];
#pragma unroll
      for (int i = 0; i < 4; i++) {
#pragma unroll
        for (int r = 0; r < 4; r++) {
          const int m = m0 + wr + i * 16 + quad * 4 + r;
          outF[(size_t)m * DIMC + o] = acc[i][j][r] + bo;
        }
      }
    }
  }
}

// ---------------------------------------------------------------------------
// Flash attention, 32x32x16 MFMA transposed compute (S^T = K Q^T, O^T = V^T P^T).
// 1-D grid of 768, bh = n % 96 (96 = 0 mod 8 -> all 8 qt-blocks of one (b,h)
// share an XCD; K/V slice HBM-fetched once, L2-served 8x).
// KVBLK=64 + LDS double-buffer, single barrier per step (T3 2-phase); bias
// rows staged to LDS; register-free staging (inverse-swizzle gld_lds).
// Unchanged from round 11 (verified: flash dropped 65 -> <56 us).
// ---------------------------------------------------------------------------
__global__ __launch_bounds__(256, 3) void flash_mfma(
    const _Float16* __restrict__ Qg, const _Float16* __restrict__ Kg,
    const _Float16* __restrict__ Vtg, const float* __restrict__ relT,
    _Float16* __restrict__ AO) {
  const int nblk = blockIdx.x;
  const int bhl = nblk % 96;                  // same-XCD group key
  const int qt = nblk / 96;                   // 0..7 (128 q rows each)
  const int head = bhl >> 3, b = bhl & 7;
  const int bh = b * NHH + head;
  const int tid = threadIdx.x, w = tid >> 6, lane = tid & 63;
  const int ql = lane & 31;                   // q column within wave tile
  const int hf = lane >> 5;                   // lane half (k/d sub-offset)

  // double-buffered K/V tiles (KVBLK=64): 2 x (8+8) KB = 32 KB
  __shared__ _Float16 Klds[2][64 * 64];       // [row][chunk^key], 8 chunks/row
  __shared__ _Float16 Vlds[2][64 * 64];       // [d-row][chunk^key], 8 chunks/row
  __shared__ __attribute__((aligned(16))) float BiasLds[2][320];  // 5 rows x 63 + pad

  // persistent Q B-frags: B[n=ql][k = s*16 + hf*8 + j]
  const int qglob = qt * 128 + w * 32 + ql;
  const _Float16* Qrow = Qg + ((size_t)bh * NSEQ + qglob) * HD + hf * 8;
  f16x8 bq[4];
#pragma unroll
  for (int s = 0; s < 4; s++) bq[s] = *(const f16x8*)(Qrow + s * 16);

  f32x16 O0 = {}, O1 = {};                    // O^T d-tiles 0..31, 32..63
  float psum = 0.f;

  const _Float16* Kbase = Kg + (size_t)bh * NSEQ * HD;
  const _Float16* Vtbase = Vtg + (size_t)bh * HD * NSEQ;

  // bias: qy fixed per wave; dy = qy - tau + 31, tau = 2*step + t
  const float* relTh = relT + (size_t)head * RELP;
  const int idxb = ql + 31 - 4 * hf;          // dx = idxb - (r&3) - 8*(r>>2)

  // V A-frag row keys (fixed per lane)
  const int vrow0 = ql, vrow1 = 32 + ql;
  const int vkey0 = (vrow0 ^ (vrow0 >> 3)) & 7;
  const int vkey1 = (vrow1 ^ (vrow1 >> 3)) & 7;

  // staging: inverse-swizzled global offsets, linear LDS dest (involution).
  int ks0, ks1, vs0, vs1;
  {
    int c = tid;
    int r = c >> 3, cc = c & 7, key = (r ^ (r >> 3)) & 7;
    ks0 = r * HD + (cc ^ key) * 8;
    vs0 = r * NSEQ + (cc ^ key) * 8;
    c = tid + 256;
    r = c >> 3; cc = c & 7; key = (r ^ (r >> 3)) & 7;
    ks1 = r * HD + (cc ^ key) * 8;
    vs1 = r * NSEQ + (cc ^ key) * 8;
  }

  // stage step s into buffer bsel (K 8KB + V 8KB + bias 316 floats)
  auto stage = [&](int s, int bsel) {
    const _Float16* Ks = Kbase + (size_t)s * 64 * HD;
    const _Float16* Vs = Vtbase + s * 64;
    gld16(Ks + ks0, &Klds[bsel][tid * 8]);
    gld16(Ks + ks1, &Klds[bsel][(tid + 256) * 8]);
    gld16(Vs + vs0, &Vlds[bsel][tid * 8]);
    gld16(Vs + vs1, &Vlds[bsel][(tid + 256) * 8]);
    if (tid < 79) {                           // 79*4 = 316 floats, contiguous
      const int dyLo = qt * 4 + 30 - 2 * s;   // in [0, 58]; span <= RELP pad
      gld16(relTh + dyLo * 63 + tid * 4, &BiasLds[bsel][tid * 4]);
    }
  };

  stage(0, 0);                                // prologue (only exposed latency)

  int cur = 0;
#pragma unroll 2
  for (int s = 0; s < 16; s++) {
    __syncthreads();                          // drains own vmcnt -> buf[cur] ready
    if (s + 1 < 16) stage(s + 1, cur ^ 1);    // in flight under compute(s)

#pragma unroll
    for (int t = 0; t < 2; t++) {
      // S^T 32x32 tile: A = K rows (t*32+ql), contraction d (64)
      const int arow = t * 32 + ql;
      const int akey = (arow ^ (arow >> 3)) & 7;
      f32x16 S = {};
      __builtin_amdgcn_s_setprio(1);
#pragma unroll
      for (int ss = 0; ss < 4; ss++) {
        const f16x8 ak = *(const f16x8*)&Klds[cur][((arow << 3) | ((ss * 2 + hf) ^ akey)) * 8];
        S = __builtin_amdgcn_mfma_f32_32x32x16_f16(ak, bq[ss], S, 0, 0, 0);
      }
      __builtin_amdgcn_s_setprio(0);

      // bias from LDS (row = w+1-t, conflict-free lane-consecutive reads)
      // p_j of group g adds relT row entry [idxb - 8g - j]
      const float* lb = &BiasLds[cur][(w + 1 - t) * 63 + idxb];
      unsigned int dw[8];
#pragma unroll
      for (int g = 0; g < 4; g++) {
        const float b0 = lb[-8 * g - 0];
        const float b1 = lb[-8 * g - 1];
        const float b2 = lb[-8 * g - 2];
        const float b3 = lb[-8 * g - 3];
        const float p0 = __expf(S[4 * g + 0] + b0);
        const float p1 = __expf(S[4 * g + 1] + b1);
        const float p2 = __expf(S[4 * g + 2] + b2);
        const float p3 = __expf(S[4 * g + 3] + b3);
        psum += (p0 + p1) + (p2 + p3);
        union { f16x4 h; unsigned int u[2]; } cv;
        cv.h[0] = (_Float16)p0; cv.h[1] = (_Float16)p1;
        cv.h[2] = (_Float16)p2; cv.h[3] = (_Float16)p3;
        dw[2 * g] = cv.u[0]; dw[2 * g + 1] = cv.u[1];
      }

      // PV: B-frag from P^T via half-exchange; A = V^T rows from LDS
      __builtin_amdgcn_s_setprio(1);
#pragma unroll
      for (int s2 = 0; s2 < 2; s2++) {
        const unsigned int x0 = hf ? dw[4 * s2 + 0] : dw[4 * s2 + 2];
        const unsigned int x1 = hf ? dw[4 * s2 + 1] : dw[4 * s2 + 3];
        const unsigned int y0 = (unsigned int)__shfl_xor((int)x0, 32, 64);
        const unsigned int y1 = (unsigned int)__shfl_xor((int)x1, 32, 64);
        union { unsigned int u[4]; f16x8 v; } bp;
        if (hf == 0) {
          bp.u[0] = dw[4 * s2 + 0]; bp.u[1] = dw[4 * s2 + 1];
          bp.u[2] = y0;             bp.u[3] = y1;
        } else {
          bp.u[0] = y0;             bp.u[1] = y1;
          bp.u[2] = dw[4 * s2 + 2]; bp.u[3] = dw[4 * s2 + 3];
        }
        const int kchunk = t * 4 + s2 * 2 + hf;
        const f16x8 av0 = *(const f16x8*)&Vlds[cur][((vrow0 << 3) | (kchunk ^ vkey0)) * 8];
        O0 = __builtin_amdgcn_mfma_f32_32x32x16_f16(av0, bp.v, O0, 0, 0, 0);
        const f16x8 av1 = *(const f16x8*)&Vlds[cur][((vrow1 << 3) | (kchunk ^ vkey1)) * 8];
        O1 = __builtin_amdgcn_mfma_f32_32x32x16_f16(av1, bp.v, O1, 0, 0, 0);
      }
      __builtin_amdgcn_s_setprio(0);
    }
    cur ^= 1;
  }

  // total row-sum for this lane's q column; divide + store O^T
  psum += __shfl_xor(psum, 32, 64);
  const float inv = 1.f / psum;
  _Float16* aoRow = AO + ((size_t)(b * NSEQ + qglob)) * DIMC + head * HD;
#pragma unroll
  for (int g = 0; g < 4; g++) {
    f16x4 o0, o1;
#pragma unroll
    for (int j = 0; j < 4; j++) {
      o0[j] = (_Float16)(O0[4 * g + j] * inv);
      o1[j] = (_Float16)(O1[4 * g + j] * inv);
    }
    const int d0 = 8 * g + 4 * hf;
    *(f16x4*)(aoRow + d0) = o0;
    *(f16x4*)(aoRow + 32 + d0) = o1;
  }
}

extern "C" void kernel_launch(void* const* d_in, const int* in_sizes, int n_in,
                              void* d_out, int out_size, void* d_ws, size_t ws_size,
                              hipStream_t stream) {
  const float* x        = (const float*)d_in[0];
  const float* qkv_w    = (const float*)d_in[1];
  const float* q_bias   = (const float*)d_in[2];
  const float* v_bias   = (const float*)d_in[3];
  const float* proj_w   = (const float*)d_in[4];
  const float* proj_b   = (const float*)d_in[5];
  const float* rel_tab  = (const float*)d_in[6];
  float* out = (float*)d_out;

  const size_t NTOK = (size_t)8 * NHH * NSEQ * HD;
  _Float16* Xb     = (_Float16*)d_ws;
  _Float16* Wqkvb  = Xb + SX;
  _Float16* Wprojb = Wqkvb + SW1;
  _Float16* Qb     = Wprojb + SW2;
  _Float16* Kb     = Qb + NTOK;
  _Float16* Vt     = Kb + NTOK;             // V written transposed by qkv gemm
  float*    relT   = (float*)(Vt + NTOK);   // 12*4032 fp32 = 193 KB
  _Float16* AOb    = Xb;                    // alias: x consumed before flash writes

  cast_f16<<<dim3(NCAST + NRELB), 256, 0, stream>>>(x, qkv_w, proj_w, Xb,
                                                    rel_tab, relT);

  gemm_mfma<0><<<dim3(64 * 18), 256, 0, stream>>>(
      Xb, Wqkvb, q_bias, v_bias, nullptr, Qb, Kb, Vt);

  flash_mfma<<<dim3(768), 256, 0, stream>>>(Qb, Kb, Vt, relT, AOb);

  gemm_mfma<1><<<dim3(64 * 6), 256, 0, stream>>>(
      AOb, Wprojb, proj_b, nullptr, out, nullptr, nullptr, nullptr);
}